// Round 1
// 536.796 us; speedup vs baseline: 3.7583x; 3.7583x over previous
//
#include <hip/hip_runtime.h>

// ---------------- workspace layout (float/int indices into d_ws) ----------
#define WS_A0 0              // commitment sum
#define WS_A1 1              // sum of E_dist over (n,c)
#define WS_A2 2              // sum of neg_ent over (n,c)
#define WS_QBAR 16           // 8192 floats: sum_n q[n,c,k]
#define WS_CBSQ (WS_QBAR + 8192)   // 8192 floats: ||cb[c,k]||^2
#define WS_IDX  (WS_CBSQ + 8192)   // 32768 ints: argmin index per (n,c)

// ---------------- output layout (floats) ----------------------------------
#define OUT_IDX  1048576     // indices (B,C,H,W) as float
#define OUT_Q    1081344     // q (N,C,K)
#define OUT_SCAL 34635776    // commitment, free_energy, confidence, balance, tau

__global__ __launch_bounds__(256) void k_cbsq(const float* __restrict__ cb,
                                              float* __restrict__ ws_f) {
  int i = blockIdx.x * 256 + threadIdx.x;   // 0..8191  (= c*1024 + k)
  const float* r = cb + (size_t)i * 32;
  float s = 0.f;
#pragma unroll
  for (int d = 0; d < 32; ++d) s = fmaf(r[d], r[d], s);
  ws_f[WS_CBSQ + i] = s;
}

__device__ __forceinline__ float wsum64(float v) {
#pragma unroll
  for (int m = 32; m >= 1; m >>= 1) v += __shfl_xor(v, m, 64);
  return v;
}

__device__ __forceinline__ float uread(float v) {
  // wave-uniform value -> SGPR (exact; all lanes hold the same bits)
  return __int_as_float(__builtin_amdgcn_readfirstlane(__float_as_int(v)));
}

// main: 256 blocks (8 c x 32 n-blocks), 512 threads (8 waves), 132KB dyn LDS.
// 132KB LDS => 1 block/CU = 8 waves = 2 waves/EU.
// NOTE (R3): the 256-VGPR budget request (launch_bounds 2nd arg, and
// amdgpu_waves_per_eu) is NOT honored (VGPR_Count pinned at 128, 3.9GB of
// scratch reads in rocprof). So the inner loop is restructured to FIT in
// 128 VGPRs: two passes over K per n, so row[32] (pass 1 streaming dot) and
// zq[32] (pass 2 accumulate) are never simultaneously live. LDS reads
// double (~165us device-wide at ds_read_b128 throughput) but ~4.2GB of
// spill traffic disappears.
__global__ __launch_bounds__(512)
__attribute__((amdgpu_waves_per_eu(2, 2)))
void k_main(
    const float* __restrict__ z, const float* __restrict__ cb,
    float* __restrict__ out, float* __restrict__ ws_f, int* __restrict__ ws_i) {
  extern __shared__ float smem[];
  float* cb_lds = smem;            // 32768 floats, xor-swizzled float4 quads
  float* qsum   = smem + 32768;    // 1024 floats: per-block sum_n q

  const int c    = blockIdx.x >> 5;
  const int nblk = blockIdx.x & 31;
  const int tid  = threadIdx.x;
  const int lane = tid & 63;
  const int wave = tid >> 6;

  // ---- stage full channel codebook into LDS, quad-xor swizzle -------------
  const float4* cb4 = (const float4*)(cb + (size_t)c * 32768);
  float4* lds4 = (float4*)cb_lds;
#pragma unroll
  for (int i = 0; i < 16; ++i) {
    int idx = i * 512 + tid;            // float4 index 0..8191
    int k = idx >> 3, q = idx & 7;
    lds4[(k << 3) + (q ^ (k & 7))] = cb4[idx];
  }
  for (int i = tid; i < 1024; i += 512) qsum[i] = 0.f;
  __syncthreads();

  const float* cbsqp = ws_f + WS_CBSQ + c * 1024;
  float* out_q   = out + OUT_Q;
  float* out_idx = out + OUT_IDX;

  float accA0 = 0.f, accA1 = 0.f, accA2 = 0.f;
  float qb[16];
#pragma unroll
  for (int jj = 0; jj < 16; ++jj) qb[jj] = 0.f;
  const int kl7 = lane & 7;

#pragma unroll 1
  for (int p = 0; p < 16; ++p) {        // each wave: 16 n, one at a time
    const int n  = nblk * 128 + wave * 16 + p;
    const int b  = n >> 10;
    const int hw = n & 1023;
    const float* zp = z + (((size_t)b * 256 + c * 32) << 10) + hw;

    // wave-uniform z -> force into SGPRs (frees 32 VGPRs)
    float zv[32];
#pragma unroll
    for (int d = 0; d < 32; ++d) zv[d] = uread(zp[d * 1024]);
    float zs = 0.f;
#pragma unroll
    for (int d = 0; d < 32; ++d) zs = fmaf(zv[d], zv[d], zs);

    // ---- pass 1: streaming dot (no row[] kept) -> e, S, es, argmax --------
    float e[16];
    float S = 0.f, es = 0.f;
    float sm = -INFINITY;
    int km = 0;

#pragma unroll 2
    for (int jj = 0; jj < 16; ++jj) {   // k = jj*64 + lane, covers K=1024
      const int k = jj * 64 + lane;
      float cq = cbsqp[k];
      float c0 = 0.f, c1 = 0.f, c2 = 0.f, c3 = 0.f;
#pragma unroll
      for (int q = 0; q < 8; ++q) {
        float4 r4 = lds4[(k << 3) + (q ^ kl7)];
        c0 = fmaf(r4.x, zv[q * 4 + 0], c0);
        c1 = fmaf(r4.y, zv[q * 4 + 1], c1);
        c2 = fmaf(r4.z, zv[q * 4 + 2], c2);
        c3 = fmaf(r4.w, zv[q * 4 + 3], c3);
      }
      float s = (c0 + c1) + (c2 + c3) - 0.5f * cq;  // logits + const(n)
      float ev = __expf(s);
      e[jj] = ev;
      S += ev;
      es = fmaf(ev, s, es);
      if (s > sm) { sm = s; km = k; }
    }

    float St = wsum64(S);
    float rS = 1.f / St;
    float est = wsum64(es);

    // ---- pass 2: re-read LDS rows; normalized q writes + q_bar + zq -------
    float zq[32];
#pragma unroll
    for (int d = 0; d < 32; ++d) zq[d] = 0.f;
    float* qp = out_q + ((size_t)n * 8 + c) * 1024;
#pragma unroll 2
    for (int jj = 0; jj < 16; ++jj) {
      const int k = jj * 64 + lane;
      float qv = e[jj] * rS;
      __builtin_nontemporal_store(qv, qp + jj * 64 + lane);
      qb[jj] += qv;
#pragma unroll
      for (int q = 0; q < 8; ++q) {
        float4 r4 = lds4[(k << 3) + (q ^ kl7)];
        zq[q * 4 + 0] = fmaf(qv, r4.x, zq[q * 4 + 0]);
        zq[q * 4 + 1] = fmaf(qv, r4.y, zq[q * 4 + 1]);
        zq[q * 4 + 2] = fmaf(qv, r4.z, zq[q * 4 + 2]);
        zq[q * 4 + 3] = fmaf(qv, r4.w, zq[q * 4 + 3]);
      }
    }

    accA1 += zs - 2.f * est * rS;              // E_dist(n)
    accA2 += est * rS - __logf(St);            // neg_ent(n) = es/S - log S

    // ---- argmax(s) == argmin(dist), tie -> lower k -------------------------
#pragma unroll
    for (int m = 32; m >= 1; m >>= 1) {
      float so = __shfl_xor(sm, m, 64); int ko = __shfl_xor(km, m, 64);
      if (so > sm || (so == sm && ko < km)) { sm = so; km = ko; }
    }
    if (lane == 0) {
      out_idx[(size_t)b * 8192 + c * 1024 + hw] = (float)km;
      ws_i[WS_IDX + n * 8 + c] = km;
    }

    // ---- split-butterfly reduce zq over 64 lanes; lane -> dd=(lane>>1)&31 --
#pragma unroll
    for (int t = 0; t < 5; ++t) {
      const int half = 16 >> t;
      const int up = (lane >> (5 - t)) & 1;
#pragma unroll
      for (int i = 0; i < half; ++i) {
        float sa = up ? zq[i] : zq[i + half];
        float ka = up ? zq[i + half] : zq[i];
        zq[i] = ka + __shfl_xor(sa, 32 >> t, 64);
      }
    }
    zq[0] += __shfl_xor(zq[0], 1, 64);
    const int ddl = (lane >> 1) & 31;
    float zf = zp[ddl * 1024];
    float d0 = zf - zq[0];               // zq already normalized by rS
    accA0 += 0.5f * wsum64(d0 * d0);  // each dd counted twice across lanes
  }

  if (lane == 0) {
    atomicAdd(&ws_f[WS_A0], accA0);
    atomicAdd(&ws_f[WS_A1], accA1);
    atomicAdd(&ws_f[WS_A2], accA2);
  }

  // ---- q_bar: registers -> LDS (one atomic pass) -> global ----------------
#pragma unroll
  for (int jj = 0; jj < 16; ++jj)
    atomicAdd(&qsum[jj * 64 + lane], qb[jj]);
  __syncthreads();
  for (int k = tid; k < 1024; k += 512)
    atomicAdd(&ws_f[WS_QBAR + c * 1024 + k], qsum[k]);
}

// hard-quantized gather: coalesced writes of cb[c, idx[n,c], dd]
__global__ __launch_bounds__(256) void k_hard(const float* __restrict__ cb,
                                              const int* __restrict__ ws_i,
                                              float* __restrict__ out0) {
  int o = blockIdx.x * 256 + threadIdx.x;    // (b, ch, hw) row-major
  int b  = o >> 18;
  int r  = o & 262143;
  int ch = r >> 10;
  int hw = r & 1023;
  int c = ch >> 5, dd = ch & 31;
  int n = (b << 10) + hw;
  int k = ws_i[WS_IDX + n * 8 + c];
  out0[o] = cb[((size_t)(c << 10) + k) * 32 + dd];
}

__global__ __launch_bounds__(256) void k_final(const float* __restrict__ ws_f,
                                               float* __restrict__ out_s) {
  __shared__ float red[256];
  int tid = threadIdx.x;
  float bal = 0.f;
  for (int i = tid; i < 8192; i += 256) {
    float qb = ws_f[WS_QBAR + i] * (1.0f / 4096.0f);
    bal += qb * __logf(qb * 1024.0f + 1e-8f);
  }
  red[tid] = bal;
  __syncthreads();
  for (int s = 128; s > 0; s >>= 1) {
    if (tid < s) red[tid] += red[tid + s];
    __syncthreads();
  }
  if (tid == 0) {
    float A0 = ws_f[WS_A0], A1 = ws_f[WS_A1], A2 = ws_f[WS_A2];
    out_s[0] = A0 * (1.0f / 1048576.0f);                              // commitment
    out_s[1] = (0.5f * A1 + A2) * (1.0f / 32768.0f) + 6.93147180559945f; // free_energy
    out_s[2] = -A2 * (1.0f / 32768.0f);                               // confidence
    out_s[3] = red[0] * 0.125f;                                       // balance
    out_s[4] = 1.0f;                                                  // tau
  }
}

extern "C" void kernel_launch(void* const* d_in, const int* in_sizes, int n_in,
                              void* d_out, int out_size, void* d_ws, size_t ws_size,
                              hipStream_t stream) {
  (void)in_sizes; (void)n_in; (void)out_size; (void)ws_size;
  const float* z  = (const float*)d_in[0];
  const float* cb = (const float*)d_in[1];
  float* out  = (float*)d_out;
  float* ws_f = (float*)d_ws;
  int*   ws_i = (int*)d_ws;

  // 132KB dynamic LDS (> 64KB default): opt in every call (idempotent, cheap)
  hipFuncSetAttribute(reinterpret_cast<const void*>(k_main),
                      hipFuncAttributeMaxDynamicSharedMemorySize, 135168);

  hipMemsetAsync(d_ws, 0, (WS_QBAR + 8192) * sizeof(float), stream);
  k_cbsq <<<32,   256, 0,      stream>>>(cb, ws_f);
  k_main <<<256,  512, 135168, stream>>>(z, cb, out, ws_f, ws_i);
  k_hard <<<4096, 256, 0,      stream>>>(cb, ws_i, out);
  k_final<<<1,    256, 0,      stream>>>(ws_f, out + OUT_SCAL);
}

// Round 2
// 525.459 us; speedup vs baseline: 3.8394x; 1.0216x over previous
//
#include <hip/hip_runtime.h>

// ---------------- workspace layout (float/int indices into d_ws) ----------
#define WS_A0 0              // commitment sum
#define WS_A1 1              // sum of E_dist over (n,c)
#define WS_A2 2              // sum of neg_ent over (n,c)
#define WS_QBAR 16           // 8192 floats: sum_n q[n,c,k]
#define WS_CBSQ (WS_QBAR + 8192)   // 8192 floats: ||cb[c,k]||^2
#define WS_IDX  (WS_CBSQ + 8192)   // 32768 ints: argmin index per (n,c)

// ---------------- output layout (floats) ----------------------------------
#define OUT_IDX  1048576     // indices (B,C,H,W) as float
#define OUT_Q    1081344     // q (N,C,K)
#define OUT_SCAL 34635776    // commitment, free_energy, confidence, balance, tau

__global__ __launch_bounds__(256) void k_cbsq(const float* __restrict__ cb,
                                              float* __restrict__ ws_f) {
  int i = blockIdx.x * 256 + threadIdx.x;   // 0..8191  (= c*1024 + k)
  const float* r = cb + (size_t)i * 32;
  float s = 0.f;
#pragma unroll
  for (int d = 0; d < 32; ++d) s = fmaf(r[d], r[d], s);
  ws_f[WS_CBSQ + i] = s;
}

__device__ __forceinline__ float wsum64(float v) {
#pragma unroll
  for (int m = 32; m >= 1; m >>= 1) v += __shfl_xor(v, m, 64);
  return v;
}

__device__ __forceinline__ float uread(float v) {
  // wave-uniform value -> SGPR (exact; all lanes hold the same bits)
  return __int_as_float(__builtin_amdgcn_readfirstlane(__float_as_int(v)));
}

// main: 256 blocks (8 c x 32 n-blocks), 512 threads (8 waves), 132KB dyn LDS.
// 132KB LDS => 1 block/CU = 8 waves = 2 waves/EU.
// R3: two-pass K-sweep so row[] and zq[] are never co-live (fits 128 VGPR,
// no scratch). R4: NB=2 n-batching — each ds_read_b128 feeds both n0 and n1
// (8 FMAs/read instead of 4), halving LDS instructions and conflict cycles.
// q_bar goes through per-pair LDS atomics instead of a qb[16] register
// accumulator to keep pass-2 pressure ~105 VGPRs.
__global__ __launch_bounds__(512)
__attribute__((amdgpu_waves_per_eu(2, 2)))
void k_main(
    const float* __restrict__ z, const float* __restrict__ cb,
    float* __restrict__ out, float* __restrict__ ws_f, int* __restrict__ ws_i) {
  extern __shared__ float smem[];
  float* cb_lds = smem;            // 32768 floats, xor-swizzled float4 quads
  float* qsum   = smem + 32768;    // 1024 floats: per-block sum_n q

  const int c    = blockIdx.x >> 5;
  const int nblk = blockIdx.x & 31;
  const int tid  = threadIdx.x;
  const int lane = tid & 63;
  const int wave = tid >> 6;

  // ---- stage full channel codebook into LDS, quad-xor swizzle -------------
  const float4* cb4 = (const float4*)(cb + (size_t)c * 32768);
  float4* lds4 = (float4*)cb_lds;
#pragma unroll
  for (int i = 0; i < 16; ++i) {
    int idx = i * 512 + tid;            // float4 index 0..8191
    int k = idx >> 3, q = idx & 7;
    lds4[(k << 3) + (q ^ (k & 7))] = cb4[idx];
  }
  for (int i = tid; i < 1024; i += 512) qsum[i] = 0.f;
  __syncthreads();

  const float* cbsqp = ws_f + WS_CBSQ + c * 1024;
  float* out_q   = out + OUT_Q;
  float* out_idx = out + OUT_IDX;

  float accA0 = 0.f, accA1 = 0.f, accA2 = 0.f;
  const int kl7 = lane & 7;

#pragma unroll 1
  for (int pp = 0; pp < 8; ++pp) {      // each wave: 8 pairs of n
    const int n0 = nblk * 128 + wave * 16 + pp * 2;
    const int n1 = n0 + 1;
    const int b0 = n0 >> 10, hw0 = n0 & 1023;
    const int b1 = n1 >> 10, hw1 = n1 & 1023;
    const float* zp0 = z + (((size_t)b0 * 256 + c * 32) << 10) + hw0;
    const float* zp1 = z + (((size_t)b1 * 256 + c * 32) << 10) + hw1;

    // wave-uniform z -> force into SGPRs
    float zv0[32], zv1[32];
#pragma unroll
    for (int d = 0; d < 32; ++d) {
      zv0[d] = uread(zp0[d * 1024]);
      zv1[d] = uread(zp1[d * 1024]);
    }
    float zs0 = 0.f, zs1 = 0.f;
#pragma unroll
    for (int d = 0; d < 32; ++d) {
      zs0 = fmaf(zv0[d], zv0[d], zs0);
      zs1 = fmaf(zv1[d], zv1[d], zs1);
    }

    // ---- pass 1: streaming dot for both n -> e, S, es, argmax -------------
    float e0[16], e1[16];
    float S0 = 0.f, S1 = 0.f, es0 = 0.f, es1 = 0.f;
    float sm0 = -INFINITY, sm1 = -INFINITY;
    int km0 = 0, km1 = 0;

#pragma unroll 2
    for (int jj = 0; jj < 16; ++jj) {   // k = jj*64 + lane, covers K=1024
      const int k = jj * 64 + lane;
      float cq = cbsqp[k];
      float a0 = 0.f, a1 = 0.f, a2 = 0.f, a3 = 0.f;
      float g0 = 0.f, g1 = 0.f, g2 = 0.f, g3 = 0.f;
#pragma unroll
      for (int q = 0; q < 8; ++q) {
        float4 r4 = lds4[(k << 3) + (q ^ kl7)];
        a0 = fmaf(r4.x, zv0[q * 4 + 0], a0);
        a1 = fmaf(r4.y, zv0[q * 4 + 1], a1);
        a2 = fmaf(r4.z, zv0[q * 4 + 2], a2);
        a3 = fmaf(r4.w, zv0[q * 4 + 3], a3);
        g0 = fmaf(r4.x, zv1[q * 4 + 0], g0);
        g1 = fmaf(r4.y, zv1[q * 4 + 1], g1);
        g2 = fmaf(r4.z, zv1[q * 4 + 2], g2);
        g3 = fmaf(r4.w, zv1[q * 4 + 3], g3);
      }
      float s0 = (a0 + a1) + (a2 + a3) - 0.5f * cq;  // logits + const(n)
      float s1 = (g0 + g1) + (g2 + g3) - 0.5f * cq;
      float ev0 = __expf(s0), ev1 = __expf(s1);
      e0[jj] = ev0; e1[jj] = ev1;
      S0 += ev0;  S1 += ev1;
      es0 = fmaf(ev0, s0, es0);
      es1 = fmaf(ev1, s1, es1);
      if (s0 > sm0) { sm0 = s0; km0 = k; }
      if (s1 > sm1) { sm1 = s1; km1 = k; }
    }

    float St0 = wsum64(S0), St1 = wsum64(S1);
    float rS0 = 1.f / St0, rS1 = 1.f / St1;
    float est0 = wsum64(es0), est1 = wsum64(es1);

    accA1 += (zs0 - 2.f * est0 * rS0) + (zs1 - 2.f * est1 * rS1);
    accA2 += (est0 * rS0 - __logf(St0)) + (est1 * rS1 - __logf(St1));

    // ---- argmax(s) == argmin(dist), tie -> lower k; retire sm/km early ----
#pragma unroll
    for (int m = 32; m >= 1; m >>= 1) {
      float so = __shfl_xor(sm0, m, 64); int ko = __shfl_xor(km0, m, 64);
      if (so > sm0 || (so == sm0 && ko < km0)) { sm0 = so; km0 = ko; }
      float sp = __shfl_xor(sm1, m, 64); int kp = __shfl_xor(km1, m, 64);
      if (sp > sm1 || (sp == sm1 && kp < km1)) { sm1 = sp; km1 = kp; }
    }
    if (lane == 0) {
      out_idx[(size_t)b0 * 8192 + c * 1024 + hw0] = (float)km0;
      ws_i[WS_IDX + n0 * 8 + c] = km0;
      out_idx[(size_t)b1 * 8192 + c * 1024 + hw1] = (float)km1;
      ws_i[WS_IDX + n1 * 8 + c] = km1;
    }

    // ---- pass 2a: e -> qv (in place), q writes, q_bar LDS atomics ---------
    float* qp0 = out_q + ((size_t)n0 * 8 + c) * 1024;
    float* qp1 = out_q + ((size_t)n1 * 8 + c) * 1024;
#pragma unroll 2
    for (int jj = 0; jj < 16; ++jj) {
      float qv0 = e0[jj] * rS0;
      float qv1 = e1[jj] * rS1;
      e0[jj] = qv0; e1[jj] = qv1;
      __builtin_nontemporal_store(qv0, qp0 + jj * 64 + lane);
      __builtin_nontemporal_store(qv1, qp1 + jj * 64 + lane);
      atomicAdd(&qsum[jj * 64 + lane], qv0 + qv1);
    }

    // ---- pass 2b: re-read LDS rows; zq accumulation for both n ------------
    float zq0[32], zq1[32];
#pragma unroll
    for (int d = 0; d < 32; ++d) { zq0[d] = 0.f; zq1[d] = 0.f; }
#pragma unroll 2
    for (int jj = 0; jj < 16; ++jj) {
      const int k = jj * 64 + lane;
      float qv0 = e0[jj], qv1 = e1[jj];
#pragma unroll
      for (int q = 0; q < 8; ++q) {
        float4 r4 = lds4[(k << 3) + (q ^ kl7)];
        zq0[q * 4 + 0] = fmaf(qv0, r4.x, zq0[q * 4 + 0]);
        zq0[q * 4 + 1] = fmaf(qv0, r4.y, zq0[q * 4 + 1]);
        zq0[q * 4 + 2] = fmaf(qv0, r4.z, zq0[q * 4 + 2]);
        zq0[q * 4 + 3] = fmaf(qv0, r4.w, zq0[q * 4 + 3]);
        zq1[q * 4 + 0] = fmaf(qv1, r4.x, zq1[q * 4 + 0]);
        zq1[q * 4 + 1] = fmaf(qv1, r4.y, zq1[q * 4 + 1]);
        zq1[q * 4 + 2] = fmaf(qv1, r4.z, zq1[q * 4 + 2]);
        zq1[q * 4 + 3] = fmaf(qv1, r4.w, zq1[q * 4 + 3]);
      }
    }

    // ---- split-butterfly reduce zq over 64 lanes; lane -> dd=(lane>>1)&31 --
#pragma unroll
    for (int t = 0; t < 5; ++t) {
      const int half = 16 >> t;
      const int up = (lane >> (5 - t)) & 1;
#pragma unroll
      for (int i = 0; i < half; ++i) {
        float sa0 = up ? zq0[i] : zq0[i + half];
        float ka0 = up ? zq0[i + half] : zq0[i];
        zq0[i] = ka0 + __shfl_xor(sa0, 32 >> t, 64);
        float sa1 = up ? zq1[i] : zq1[i + half];
        float ka1 = up ? zq1[i + half] : zq1[i];
        zq1[i] = ka1 + __shfl_xor(sa1, 32 >> t, 64);
      }
    }
    zq0[0] += __shfl_xor(zq0[0], 1, 64);
    zq1[0] += __shfl_xor(zq1[0], 1, 64);
    const int ddl = (lane >> 1) & 31;
    float zf0 = zp0[ddl * 1024];
    float zf1 = zp1[ddl * 1024];
    float d0 = zf0 - zq0[0];             // zq already normalized (qv = e*rS)
    float d1 = zf1 - zq1[0];
    accA0 += 0.5f * wsum64(d0 * d0 + d1 * d1);  // each dd counted twice
  }

  if (lane == 0) {
    atomicAdd(&ws_f[WS_A0], accA0);
    atomicAdd(&ws_f[WS_A1], accA1);
    atomicAdd(&ws_f[WS_A2], accA2);
  }

  // ---- q_bar: block LDS accumulator -> global -----------------------------
  __syncthreads();
  for (int k = tid; k < 1024; k += 512)
    atomicAdd(&ws_f[WS_QBAR + c * 1024 + k], qsum[k]);
}

// hard-quantized gather: coalesced writes of cb[c, idx[n,c], dd]
__global__ __launch_bounds__(256) void k_hard(const float* __restrict__ cb,
                                              const int* __restrict__ ws_i,
                                              float* __restrict__ out0) {
  int o = blockIdx.x * 256 + threadIdx.x;    // (b, ch, hw) row-major
  int b  = o >> 18;
  int r  = o & 262143;
  int ch = r >> 10;
  int hw = r & 1023;
  int c = ch >> 5, dd = ch & 31;
  int n = (b << 10) + hw;
  int k = ws_i[WS_IDX + n * 8 + c];
  out0[o] = cb[((size_t)(c << 10) + k) * 32 + dd];
}

__global__ __launch_bounds__(256) void k_final(const float* __restrict__ ws_f,
                                               float* __restrict__ out_s) {
  __shared__ float red[256];
  int tid = threadIdx.x;
  float bal = 0.f;
  for (int i = tid; i < 8192; i += 256) {
    float qb = ws_f[WS_QBAR + i] * (1.0f / 4096.0f);
    bal += qb * __logf(qb * 1024.0f + 1e-8f);
  }
  red[tid] = bal;
  __syncthreads();
  for (int s = 128; s > 0; s >>= 1) {
    if (tid < s) red[tid] += red[tid + s];
    __syncthreads();
  }
  if (tid == 0) {
    float A0 = ws_f[WS_A0], A1 = ws_f[WS_A1], A2 = ws_f[WS_A2];
    out_s[0] = A0 * (1.0f / 1048576.0f);                              // commitment
    out_s[1] = (0.5f * A1 + A2) * (1.0f / 32768.0f) + 6.93147180559945f; // free_energy
    out_s[2] = -A2 * (1.0f / 32768.0f);                               // confidence
    out_s[3] = red[0] * 0.125f;                                       // balance
    out_s[4] = 1.0f;                                                  // tau
  }
}

extern "C" void kernel_launch(void* const* d_in, const int* in_sizes, int n_in,
                              void* d_out, int out_size, void* d_ws, size_t ws_size,
                              hipStream_t stream) {
  (void)in_sizes; (void)n_in; (void)out_size; (void)ws_size;
  const float* z  = (const float*)d_in[0];
  const float* cb = (const float*)d_in[1];
  float* out  = (float*)d_out;
  float* ws_f = (float*)d_ws;
  int*   ws_i = (int*)d_ws;

  // 132KB dynamic LDS (> 64KB default): opt in every call (idempotent, cheap)
  hipFuncSetAttribute(reinterpret_cast<const void*>(k_main),
                      hipFuncAttributeMaxDynamicSharedMemorySize, 135168);

  hipMemsetAsync(d_ws, 0, (WS_QBAR + 8192) * sizeof(float), stream);
  k_cbsq <<<32,   256, 0,      stream>>>(cb, ws_f);
  k_main <<<256,  512, 135168, stream>>>(z, cb, out, ws_f, ws_i);
  k_hard <<<4096, 256, 0,      stream>>>(cb, ws_i, out);
  k_final<<<1,    256, 0,      stream>>>(ws_f, out + OUT_SCAL);
}

// Round 3
// 521.574 us; speedup vs baseline: 3.8680x; 1.0074x over previous
//
#include <hip/hip_runtime.h>

// ---------------- workspace layout (float/int indices into d_ws) ----------
#define WS_A0 0              // commitment sum
#define WS_A1 1              // sum of E_dist over (n,c)
#define WS_A2 2              // sum of neg_ent over (n,c)
#define WS_QBAR 16           // 8192 floats: sum_n q[n,c,k]
#define WS_CBSQ (WS_QBAR + 8192)   // 8192 floats: ||cb[c,k]||^2
#define WS_IDX  (WS_CBSQ + 8192)   // 32768 ints: argmin index per (n,c)

// ---------------- output layout (floats) ----------------------------------
#define OUT_IDX  1048576     // indices (B,C,H,W) as float
#define OUT_Q    1081344     // q (N,C,K)
#define OUT_SCAL 34635776    // commitment, free_energy, confidence, balance, tau

__global__ __launch_bounds__(256) void k_cbsq(const float* __restrict__ cb,
                                              float* __restrict__ ws_f) {
  int i = blockIdx.x * 256 + threadIdx.x;   // 0..8191  (= c*1024 + k)
  const float* r = cb + (size_t)i * 32;
  float s = 0.f;
#pragma unroll
  for (int d = 0; d < 32; ++d) s = fmaf(r[d], r[d], s);
  ws_f[WS_CBSQ + i] = s;
}

__device__ __forceinline__ float wsum64(float v) {
#pragma unroll
  for (int m = 32; m >= 1; m >>= 1) v += __shfl_xor(v, m, 64);
  return v;
}

__device__ __forceinline__ float uread(float v) {
  // wave-uniform value -> SGPR (exact; all lanes hold the same bits)
  return __int_as_float(__builtin_amdgcn_readfirstlane(__float_as_int(v)));
}

// main: 256 blocks (8 c x 32 n-blocks), 1024 threads (16 waves), 152.5KB LDS.
// R3: two-pass K-sweep fits 128 VGPR (no scratch). R4: NB=2 n-batching.
// R5: kernel was LATENCY-bound (2 waves/EU; FMA floor 27us, LDS 109us,
// wall 408us). Fixes: (a) 1024-thr blocks -> 4 waves/EU at the same
// 128-VGPR budget (16 waves x 128 = 2048 = full CU pool); (b) cbsq staged
// to LDS (kills 16 lane-strided global loads per pair inside jj-loop);
// (c) block z-slice staged to LDS, +1-padded (kills 64 uniform global
// loads per pair prologue + zf re-read).
#define ZLD 33               // z_lds leading dim (+1 pad: write stride 33)
__global__ __launch_bounds__(1024)
__attribute__((amdgpu_waves_per_eu(4, 4)))
void k_main(
    const float* __restrict__ z, const float* __restrict__ cb,
    float* __restrict__ out, float* __restrict__ ws_f, int* __restrict__ ws_i) {
  extern __shared__ float smem[];
  float* cb_lds   = smem;              // 32768 floats, xor-swizzled quads
  float* qsum     = smem + 32768;      // 1024 floats: per-block sum_n q
  float* cbsq_lds = smem + 33792;      // 1024 floats: ||cb[c,k]||^2
  float* z_lds    = smem + 34816;      // 128*33 floats: z[nl, d] (padded)

  const int c    = blockIdx.x >> 5;
  const int nblk = blockIdx.x & 31;
  const int tid  = threadIdx.x;
  const int lane = tid & 63;
  const int wave = tid >> 6;           // 0..15

  const int bb   = (nblk * 128) >> 10;      // batch index, constant per block
  const int hwb  = (nblk * 128) & 1023;     // hw base, constant per block

  // ---- stage full channel codebook into LDS, quad-xor swizzle -------------
  const float4* cb4 = (const float4*)(cb + (size_t)c * 32768);
  float4* lds4 = (float4*)cb_lds;
#pragma unroll
  for (int i = 0; i < 8; ++i) {
    int idx = i * 1024 + tid;           // float4 index 0..8191
    int k = idx >> 3, q = idx & 7;
    lds4[(k << 3) + (q ^ (k & 7))] = cb4[idx];
  }
  qsum[tid] = 0.f;
  cbsq_lds[tid] = ws_f[WS_CBSQ + c * 1024 + tid];
  // z slice: 128 n x 32 d, coalesced global reads, padded LDS writes
  {
    const float* zbase = z + (((size_t)bb * 256 + c * 32) << 10) + hwb;
#pragma unroll
    for (int i = 0; i < 4; ++i) {
      int idx = i * 1024 + tid;         // 0..4095
      int d = idx >> 7, j = idx & 127;
      z_lds[j * ZLD + d] = zbase[(size_t)d * 1024 + j];
    }
  }
  __syncthreads();

  float* out_q   = out + OUT_Q;
  float* out_idx = out + OUT_IDX;

  float accA0 = 0.f, accA1 = 0.f, accA2 = 0.f;
  const int kl7 = lane & 7;

#pragma unroll 1
  for (int pp = 0; pp < 4; ++pp) {      // each wave: 4 pairs of n
    const int nl0 = wave * 8 + pp * 2;  // local n in [0,128)
    const int nl1 = nl0 + 1;
    const int n0 = nblk * 128 + nl0;
    const int n1 = n0 + 1;

    // wave-uniform z (LDS broadcast) -> force into SGPRs
    float zv0[32], zv1[32];
#pragma unroll
    for (int d = 0; d < 32; ++d) {
      zv0[d] = uread(z_lds[nl0 * ZLD + d]);
      zv1[d] = uread(z_lds[nl1 * ZLD + d]);
    }
    float zs0 = 0.f, zs1 = 0.f;
#pragma unroll
    for (int d = 0; d < 32; ++d) {
      zs0 = fmaf(zv0[d], zv0[d], zs0);
      zs1 = fmaf(zv1[d], zv1[d], zs1);
    }

    // ---- pass 1: streaming dot for both n -> e, S, es, argmax -------------
    float e0[16], e1[16];
    float S0 = 0.f, S1 = 0.f, es0 = 0.f, es1 = 0.f;
    float sm0 = -INFINITY, sm1 = -INFINITY;
    int km0 = 0, km1 = 0;

#pragma unroll 2
    for (int jj = 0; jj < 16; ++jj) {   // k = jj*64 + lane, covers K=1024
      const int k = jj * 64 + lane;
      float cq = cbsq_lds[k];
      float a0 = 0.f, a1 = 0.f, a2 = 0.f, a3 = 0.f;
      float g0 = 0.f, g1 = 0.f, g2 = 0.f, g3 = 0.f;
#pragma unroll
      for (int q = 0; q < 8; ++q) {
        float4 r4 = lds4[(k << 3) + (q ^ kl7)];
        a0 = fmaf(r4.x, zv0[q * 4 + 0], a0);
        a1 = fmaf(r4.y, zv0[q * 4 + 1], a1);
        a2 = fmaf(r4.z, zv0[q * 4 + 2], a2);
        a3 = fmaf(r4.w, zv0[q * 4 + 3], a3);
        g0 = fmaf(r4.x, zv1[q * 4 + 0], g0);
        g1 = fmaf(r4.y, zv1[q * 4 + 1], g1);
        g2 = fmaf(r4.z, zv1[q * 4 + 2], g2);
        g3 = fmaf(r4.w, zv1[q * 4 + 3], g3);
      }
      float s0 = (a0 + a1) + (a2 + a3) - 0.5f * cq;  // logits + const(n)
      float s1 = (g0 + g1) + (g2 + g3) - 0.5f * cq;
      float ev0 = __expf(s0), ev1 = __expf(s1);
      e0[jj] = ev0; e1[jj] = ev1;
      S0 += ev0;  S1 += ev1;
      es0 = fmaf(ev0, s0, es0);
      es1 = fmaf(ev1, s1, es1);
      if (s0 > sm0) { sm0 = s0; km0 = k; }
      if (s1 > sm1) { sm1 = s1; km1 = k; }
    }

    float St0 = wsum64(S0), St1 = wsum64(S1);
    float rS0 = 1.f / St0, rS1 = 1.f / St1;
    float est0 = wsum64(es0), est1 = wsum64(es1);

    accA1 += (zs0 - 2.f * est0 * rS0) + (zs1 - 2.f * est1 * rS1);
    accA2 += (est0 * rS0 - __logf(St0)) + (est1 * rS1 - __logf(St1));

    // ---- argmax(s) == argmin(dist), tie -> lower k; retire sm/km early ----
#pragma unroll
    for (int m = 32; m >= 1; m >>= 1) {
      float so = __shfl_xor(sm0, m, 64); int ko = __shfl_xor(km0, m, 64);
      if (so > sm0 || (so == sm0 && ko < km0)) { sm0 = so; km0 = ko; }
      float sp = __shfl_xor(sm1, m, 64); int kp = __shfl_xor(km1, m, 64);
      if (sp > sm1 || (sp == sm1 && kp < km1)) { sm1 = sp; km1 = kp; }
    }
    if (lane == 0) {
      out_idx[(size_t)bb * 8192 + c * 1024 + hwb + nl0] = (float)km0;
      ws_i[WS_IDX + n0 * 8 + c] = km0;
      out_idx[(size_t)bb * 8192 + c * 1024 + hwb + nl1] = (float)km1;
      ws_i[WS_IDX + n1 * 8 + c] = km1;
    }

    // ---- pass 2a: e -> qv (in place), q writes, q_bar LDS atomics ---------
    float* qp0 = out_q + ((size_t)n0 * 8 + c) * 1024;
    float* qp1 = out_q + ((size_t)n1 * 8 + c) * 1024;
#pragma unroll 2
    for (int jj = 0; jj < 16; ++jj) {
      float qv0 = e0[jj] * rS0;
      float qv1 = e1[jj] * rS1;
      e0[jj] = qv0; e1[jj] = qv1;
      __builtin_nontemporal_store(qv0, qp0 + jj * 64 + lane);
      __builtin_nontemporal_store(qv1, qp1 + jj * 64 + lane);
      atomicAdd(&qsum[jj * 64 + lane], qv0 + qv1);
    }

    // ---- pass 2b: re-read LDS rows; zq accumulation for both n ------------
    float zq0[32], zq1[32];
#pragma unroll
    for (int d = 0; d < 32; ++d) { zq0[d] = 0.f; zq1[d] = 0.f; }
#pragma unroll 2
    for (int jj = 0; jj < 16; ++jj) {
      const int k = jj * 64 + lane;
      float qv0 = e0[jj], qv1 = e1[jj];
#pragma unroll
      for (int q = 0; q < 8; ++q) {
        float4 r4 = lds4[(k << 3) + (q ^ kl7)];
        zq0[q * 4 + 0] = fmaf(qv0, r4.x, zq0[q * 4 + 0]);
        zq0[q * 4 + 1] = fmaf(qv0, r4.y, zq0[q * 4 + 1]);
        zq0[q * 4 + 2] = fmaf(qv0, r4.z, zq0[q * 4 + 2]);
        zq0[q * 4 + 3] = fmaf(qv0, r4.w, zq0[q * 4 + 3]);
        zq1[q * 4 + 0] = fmaf(qv1, r4.x, zq1[q * 4 + 0]);
        zq1[q * 4 + 1] = fmaf(qv1, r4.y, zq1[q * 4 + 1]);
        zq1[q * 4 + 2] = fmaf(qv1, r4.z, zq1[q * 4 + 2]);
        zq1[q * 4 + 3] = fmaf(qv1, r4.w, zq1[q * 4 + 3]);
      }
    }

    // ---- split-butterfly reduce zq over 64 lanes; lane -> dd=(lane>>1)&31 --
#pragma unroll
    for (int t = 0; t < 5; ++t) {
      const int half = 16 >> t;
      const int up = (lane >> (5 - t)) & 1;
#pragma unroll
      for (int i = 0; i < half; ++i) {
        float sa0 = up ? zq0[i] : zq0[i + half];
        float ka0 = up ? zq0[i + half] : zq0[i];
        zq0[i] = ka0 + __shfl_xor(sa0, 32 >> t, 64);
        float sa1 = up ? zq1[i] : zq1[i + half];
        float ka1 = up ? zq1[i + half] : zq1[i];
        zq1[i] = ka1 + __shfl_xor(sa1, 32 >> t, 64);
      }
    }
    zq0[0] += __shfl_xor(zq0[0], 1, 64);
    zq1[0] += __shfl_xor(zq1[0], 1, 64);
    const int ddl = (lane >> 1) & 31;
    float zf0 = z_lds[nl0 * ZLD + ddl];
    float zf1 = z_lds[nl1 * ZLD + ddl];
    float d0 = zf0 - zq0[0];             // zq already normalized (qv = e*rS)
    float d1 = zf1 - zq1[0];
    accA0 += 0.5f * wsum64(d0 * d0 + d1 * d1);  // each dd counted twice
  }

  if (lane == 0) {
    atomicAdd(&ws_f[WS_A0], accA0);
    atomicAdd(&ws_f[WS_A1], accA1);
    atomicAdd(&ws_f[WS_A2], accA2);
  }

  // ---- q_bar: block LDS accumulator -> global -----------------------------
  __syncthreads();
  atomicAdd(&ws_f[WS_QBAR + c * 1024 + tid], qsum[tid]);
}

// hard-quantized gather: coalesced writes of cb[c, idx[n,c], dd]
__global__ __launch_bounds__(256) void k_hard(const float* __restrict__ cb,
                                              const int* __restrict__ ws_i,
                                              float* __restrict__ out0) {
  int o = blockIdx.x * 256 + threadIdx.x;    // (b, ch, hw) row-major
  int b  = o >> 18;
  int r  = o & 262143;
  int ch = r >> 10;
  int hw = r & 1023;
  int c = ch >> 5, dd = ch & 31;
  int n = (b << 10) + hw;
  int k = ws_i[WS_IDX + n * 8 + c];
  out0[o] = cb[((size_t)(c << 10) + k) * 32 + dd];
}

__global__ __launch_bounds__(256) void k_final(const float* __restrict__ ws_f,
                                               float* __restrict__ out_s) {
  __shared__ float red[256];
  int tid = threadIdx.x;
  float bal = 0.f;
  for (int i = tid; i < 8192; i += 256) {
    float qb = ws_f[WS_QBAR + i] * (1.0f / 4096.0f);
    bal += qb * __logf(qb * 1024.0f + 1e-8f);
  }
  red[tid] = bal;
  __syncthreads();
  for (int s = 128; s > 0; s >>= 1) {
    if (tid < s) red[tid] += red[tid + s];
    __syncthreads();
  }
  if (tid == 0) {
    float A0 = ws_f[WS_A0], A1 = ws_f[WS_A1], A2 = ws_f[WS_A2];
    out_s[0] = A0 * (1.0f / 1048576.0f);                              // commitment
    out_s[1] = (0.5f * A1 + A2) * (1.0f / 32768.0f) + 6.93147180559945f; // free_energy
    out_s[2] = -A2 * (1.0f / 32768.0f);                               // confidence
    out_s[3] = red[0] * 0.125f;                                       // balance
    out_s[4] = 1.0f;                                                  // tau
  }
}

extern "C" void kernel_launch(void* const* d_in, const int* in_sizes, int n_in,
                              void* d_out, int out_size, void* d_ws, size_t ws_size,
                              hipStream_t stream) {
  (void)in_sizes; (void)n_in; (void)out_size; (void)ws_size;
  const float* z  = (const float*)d_in[0];
  const float* cb = (const float*)d_in[1];
  float* out  = (float*)d_out;
  float* ws_f = (float*)d_ws;
  int*   ws_i = (int*)d_ws;

  // 152.5KB dynamic LDS (> 64KB default): opt in every call (idempotent)
  hipFuncSetAttribute(reinterpret_cast<const void*>(k_main),
                      hipFuncAttributeMaxDynamicSharedMemorySize, 156160);

  hipMemsetAsync(d_ws, 0, (WS_QBAR + 8192) * sizeof(float), stream);
  k_cbsq <<<32,   256, 0,      stream>>>(cb, ws_f);
  k_main <<<256, 1024, 156160, stream>>>(z, cb, out, ws_f, ws_i);
  k_hard <<<4096, 256, 0,      stream>>>(cb, ws_i, out);
  k_final<<<1,    256, 0,      stream>>>(ws_f, out + OUT_SCAL);
}